// Round 10
// baseline (343.499 us; speedup 1.0000x reference)
//
#include <hip/hip_runtime.h>
#include <hip/hip_bf16.h>

#define NN 50000
#define NE 800000
#define DD 128
#define NB 196             // ceil(NN/256)
#define NSB 49             // ceil(NN/1024)
#define PH (64 * NB)       // degree-bucket histogram size = 12544
#define FS 1024            // edges per slice (hist + fill partitioning)
#define NSL 782            // ceil(NE/FS)
#define HHB NSL            // hist blocks (each edge read ONCE)
#define QB 3125            // quant-cast blocks (NN/16)
#define WB 192             // wtcast blocks
#define LG 3125            // layer grid (16 nodes/block, 256 threads)
#define LN_EPS 1e-5f

typedef __bf16 bf16x8 __attribute__((ext_vector_type(8)));
typedef float f32x4 __attribute__((ext_vector_type(4)));

__device__ inline ushort f2bf_bits(float f) {
    union { __hip_bfloat16 h; ushort u; } c;
    c.h = __float2bfloat16(f);
    return c.u;
}

// dequant-accumulate 16 int8 lanes of one uint4 with weight ww
__device__ inline void accum_q16(float* acc, uint4 v, float ww) {
    uint q0 = v.x, q1 = v.y, q2 = v.z, q3 = v.w;
    acc[0]  = fmaf(ww, (float)(char)(q0), acc[0]);
    acc[1]  = fmaf(ww, (float)(char)(q0 >> 8), acc[1]);
    acc[2]  = fmaf(ww, (float)(char)(q0 >> 16), acc[2]);
    acc[3]  = fmaf(ww, (float)(char)(q0 >> 24), acc[3]);
    acc[4]  = fmaf(ww, (float)(char)(q1), acc[4]);
    acc[5]  = fmaf(ww, (float)(char)(q1 >> 8), acc[5]);
    acc[6]  = fmaf(ww, (float)(char)(q1 >> 16), acc[6]);
    acc[7]  = fmaf(ww, (float)(char)(q1 >> 24), acc[7]);
    acc[8]  = fmaf(ww, (float)(char)(q2), acc[8]);
    acc[9]  = fmaf(ww, (float)(char)(q2 >> 8), acc[9]);
    acc[10] = fmaf(ww, (float)(char)(q2 >> 16), acc[10]);
    acc[11] = fmaf(ww, (float)(char)(q2 >> 24), acc[11]);
    acc[12] = fmaf(ww, (float)(char)(q3), acc[12]);
    acc[13] = fmaf(ww, (float)(char)(q3 >> 8), acc[13]);
    acc[14] = fmaf(ww, (float)(char)(q3 >> 16), acc[14]);
    acc[15] = fmaf(ww, (float)(char)(q3 >> 24), acc[15]);
}

// ---- fused: single-pass hist (rank-capturing, each edge read ONCE) + int8 row-quant
// cast + Wt cast ---- (r8 structure verbatim: best measured preamble)
__global__ void hist_cast_kernel(const int* __restrict__ dst, int* __restrict__ counts,
                                 int* __restrict__ rank, const float* __restrict__ x,
                                 uint2* __restrict__ qf0, float* __restrict__ sc0,
                                 const float* __restrict__ W, ushort* __restrict__ Wt) {
    int b = blockIdx.x;
    if (b < HHB) {
        int base = b * FS;
#pragma unroll 4
        for (int i = threadIdx.x; i < FS; i += 256) {
            int e = base + i;
            if (e < NE) rank[e] = atomicAdd(&counts[dst[e]], 1);
        }
    } else if (b < HHB + QB) {
        // per-node int8 quantization: 16 lanes x 8 floats = one 128-elem row
        int bb = b - HHB;
        int group = threadIdx.x >> 4, t = threadIdx.x & 15;
        int node = bb * 16 + group;  // 3125*16 = 50000 exact
        const float4* xr = (const float4*)(x + (size_t)node * DD + t * 8);
        float4 v0 = xr[0], v1 = xr[1];
        float vals[8] = {v0.x, v0.y, v0.z, v0.w, v1.x, v1.y, v1.z, v1.w};
        float am = 0.f;
#pragma unroll
        for (int i = 0; i < 8; ++i) am = fmaxf(am, fabsf(vals[i]));
#pragma unroll
        for (int off = 1; off <= 8; off <<= 1) am = fmaxf(am, __shfl_xor(am, off, 64));
        float inv = 127.f / fmaxf(am, 1e-20f);
        uint lo = 0, hi = 0;
#pragma unroll
        for (int i = 0; i < 4; ++i) {
            int q = __float2int_rn(vals[i] * inv);
            lo |= ((uint)(q & 0xff)) << (8 * i);
        }
#pragma unroll
        for (int i = 0; i < 4; ++i) {
            int q = __float2int_rn(vals[4 + i] * inv);
            hi |= ((uint)(q & 0xff)) << (8 * i);
        }
        uint2 pk; pk.x = lo; pk.y = hi;
        qf0[node * 16 + t] = pk;
        if (t == 0) sc0[node] = am / 127.f;
    } else {
        int i = (b - HHB - QB) * 256 + threadIdx.x;  // 3*128*128 = 49152
        int l = i >> 14, k = (i >> 7) & 127, n = i & 127;
        Wt[l * 16384 + n * 128 + k] = f2bf_bits(W[i]);
    }
}

// level-0 scan over NN elements, 1024 threads/block, in-place; emits block sums
__global__ __launch_bounds__(1024) void scan1024_blocks(int* __restrict__ data,
                                                        int* __restrict__ bsums) {
    __shared__ int ws[16];
    int gid = blockIdx.x * 1024 + threadIdx.x;
    int lane = threadIdx.x & 63, wid = threadIdx.x >> 6;
    int v = (gid < NN) ? data[gid] : 0;
    int x = v;
#pragma unroll
    for (int off = 1; off < 64; off <<= 1) {
        int t = __shfl_up(x, off, 64);
        if (lane >= off) x += t;
    }
    if (lane == 63) ws[wid] = x;
    __syncthreads();
    if (threadIdx.x == 0) {
        int run = 0;
        for (int i = 0; i < 16; ++i) { int t = ws[i]; ws[i] = run; run += t; }
        bsums[blockIdx.x] = run;
    }
    __syncthreads();
    if (gid < NN) data[gid] = x - v + ws[wid];
}

// level-1: single block scans the 49 block sums
__global__ __launch_bounds__(1024) void scan_sums1024(int* __restrict__ bsums, int nb) {
    __shared__ int ws[16];
    int tid = threadIdx.x;
    int lane = tid & 63, wid = tid >> 6;
    int v = (tid < nb) ? bsums[tid] : 0;
    int x = v;
#pragma unroll
    for (int off = 1; off < 64; off <<= 1) {
        int t = __shfl_up(x, off, 64);
        if (lane >= off) x += t;
    }
    if (lane == 63) ws[wid] = x;
    __syncthreads();
    if (tid == 0) {
        int run = 0;
        for (int i = 0; i < 16; ++i) { int t = ws[i]; ws[i] = run; run += t; }
    }
    __syncthreads();
    if (tid < nb) bsums[tid] = x - v + ws[wid];
}

// row_ptr, degree, dinv + degree histogram (bins reversed -> longest-job-first layer
// scheduling; numerics unaffected).
__global__ void finalize_kernel(const int* __restrict__ excl, const int* __restrict__ bsums,
                                int* __restrict__ row_ptr, float* __restrict__ dinv,
                                int* __restrict__ degarr, int* __restrict__ bh) {
    __shared__ int lh[64];
    if (threadIdx.x < 64) lh[threadIdx.x] = 0;
    __syncthreads();
    int d = blockIdx.x * 256 + threadIdx.x;
    if (d < NN) {
        int p0 = excl[d] + bsums[d >> 10];
        int nxt = (d == NN - 1) ? NE : excl[d + 1] + bsums[(d + 1) >> 10];
        int deg = nxt - p0;
        row_ptr[d] = p0;
        dinv[d] = rsqrtf((float)deg + 1.0f);
        degarr[d] = deg;
        atomicAdd(&lh[63 - min(deg, 63)], 1);
    }
    __syncthreads();
    if (threadIdx.x < 64) bh[threadIdx.x * NB + blockIdx.x] = lh[threadIdx.x];
    if (blockIdx.x == 0 && threadIdx.x == 0) row_ptr[NN] = NE;
}

__global__ __launch_bounds__(1024) void permscan_kernel(int* __restrict__ bh) {
    __shared__ int wsum[16];
    const int CH = 13;  // 1024*13 = 13312 >= 12544
    int tid = threadIdx.x;
    int base = tid * CH;
    int vals[CH];
    int s = 0;
#pragma unroll
    for (int i = 0; i < CH; ++i) {
        int idx = base + i;
        int v = (idx < PH) ? bh[idx] : 0;
        vals[i] = s;
        s += v;
    }
    int lane = tid & 63, wid = tid >> 6;
    int x = s;
#pragma unroll
    for (int off = 1; off < 64; off <<= 1) {
        int t = __shfl_up(x, off, 64);
        if (lane >= off) x += t;
    }
    if (lane == 63) wsum[wid] = x;
    __syncthreads();
    if (tid == 0) {
        int run = 0;
        for (int i = 0; i < 16; ++i) { int t = wsum[i]; wsum[i] = run; run += t; }
    }
    __syncthreads();
    int texcl = x - s + wsum[wid];
#pragma unroll
    for (int i = 0; i < CH; ++i) {
        int idx = base + i;
        if (idx < PH) bh[idx] = texcl + vals[i];
    }
}

// merged: blocks [0,NB) = degree-bucket permscatter (descending degree); blocks [NB,..) =
// single-pass fill (each edge read ONCE), atomic-free: pos = excl[d] + bsums + rank[e].
// Block NB zero-inits 8 edge2 slack entries (safe over-read for the last node's batches).
__global__ void scatter_fill_kernel(const int* __restrict__ degarr, const int* __restrict__ bh,
                                    int* __restrict__ perm, const int* __restrict__ src,
                                    const int* __restrict__ dst, const int* __restrict__ excl,
                                    const int* __restrict__ bsums, const int* __restrict__ rank,
                                    const float* __restrict__ dinv, int2* __restrict__ edge2) {
    if (blockIdx.x < NB) {
        __shared__ int lh[64];
        __shared__ int lbase[64];
        if (threadIdx.x < 64) {
            lh[threadIdx.x] = 0;
            lbase[threadIdx.x] = bh[threadIdx.x * NB + blockIdx.x];
        }
        __syncthreads();
        int gid = blockIdx.x * 256 + threadIdx.x;
        if (gid < NN) {
            int b = 63 - min(degarr[gid], 63);
            int r = atomicAdd(&lh[b], 1);
            perm[lbase[b] + r] = gid;
        }
    } else {
        int bb = blockIdx.x - NB;
        if (bb == 0 && threadIdx.x < 8) {
            int2 z; z.x = 0; z.y = 0;
            edge2[NE + threadIdx.x] = z;
        }
        int base = bb * FS;
#pragma unroll 4
        for (int i = threadIdx.x; i < FS; i += 256) {
            int e = base + i;
            if (e < NE) {
                int d = dst[e];
                int s = src[e];
                int pos = excl[d] + bsums[d >> 10] + rank[e];
                int2 o;
                o.x = s;
                o.y = __float_as_int(dinv[s] * dinv[d]);
                edge2[pos] = o;
            }
        }
    }
}

// ---------------- fused per-layer: int8 gather-aggregate + MFMA GEMM + bias+LN+ReLU+res ----
// OCCUPANCY CHANGE: each node's edge list is split across TWO 8-lane groups (first/second
// half of the batch range); block = 256 threads = 4 waves = 16 nodes -> 8 blocks/CU = 32
// waves/CU (full) and the per-node serial chain halves. The halves' f32 partials combine
// via LDS before the bf16 pack. Gather inner loop is r6's proven form (full 128 B row per
// gather instr, edge meta via one distributed load + shfl).
template <bool RES, bool FINAL>
__global__ __launch_bounds__(256, 8) void layer_kernel(
    const uint4* __restrict__ qin, const float* __restrict__ scin,
    const ushort* __restrict__ fin, const int* __restrict__ row_ptr,
    const int2* __restrict__ edge2, const int* __restrict__ perm,
    const float* __restrict__ dinv, const ushort* __restrict__ Wt,
    const float* __restrict__ bias, const float* __restrict__ gamma,
    const float* __restrict__ beta, ushort* __restrict__ fout, char* __restrict__ qfout,
    float* __restrict__ scout, float* __restrict__ out) {
    __shared__ uint4 sA[16 * 17];
    __shared__ float pB[16][132];   // f32 partials of half-1 groups (+4 pad)
    __shared__ int sNode[16];
    __shared__ float sLN1[4][16], sLN2[4][16];
    __shared__ float sMX[4][16];

    int tid = threadIdx.x;
    int wv = tid >> 6, lane = tid & 63;
    int grp8 = lane >> 3, ln = lane & 7;
    int gg = wv * 8 + grp8;          // 0..31 (8-lane group id)
    int nslot = gg >> 1, half = gg & 1;
    int slot = blockIdx.x * 16 + nslot;  // grid 3125*16 = 50000 exact
    int node = perm[slot];
    if (ln == 0 && half == 0) sNode[nslot] = node;

    // ---- phase 1: int8 gather-aggregate, 2 groups per node (batch range halved) ----
    {
        int beg = row_ptr[node], deg = row_ptr[node + 1] - beg;
        int nbt = (deg + 7) >> 3;
        int nb2 = (nbt + 1) >> 1;
        int bA = half ? nb2 : 0;
        int bZ = half ? nbt : nb2;
        float acc[16] = {};

        uint4 qself;
        float wself = 0.f;
        if (half == 0) {
            qself = qin[node * 8 + ln];  // issued first, consumed last
            float di = dinv[node];
            wself = di * di * scin[node];
        }

        const int2* eb = edge2 + beg;
        int bsel = lane & 56;
        for (int b = bA; b < bZ; ++b) {
            int lim = deg - b * 8;  // >= 1 for all executed batches
            int2 a = eb[b * 8 + ln];  // own edge (over-read covered by edge2 slack)
            float wf = __int_as_float(a.y) * scin[a.x];
            int sj[8];
            float W8[8];
#pragma unroll
            for (int j = 0; j < 8; ++j) sj[j] = __shfl(a.x, bsel + j, 64);
#pragma unroll
            for (int j = 0; j < 8; ++j) W8[j] = __shfl(wf, bsel + j, 64);
            uint4 Q[8];
#pragma unroll
            for (int j = 0; j < 8; ++j) Q[j] = qin[sj[j] * 8 + ln];
#pragma unroll
            for (int j = 0; j < 8; ++j) accum_q16(acc, Q[j], (j < lim) ? W8[j] : 0.f);
        }

        if (half == 1) {
            float4* d4 = (float4*)&pB[nslot][ln * 16];
            d4[0] = (float4){acc[0], acc[1], acc[2], acc[3]};
            d4[1] = (float4){acc[4], acc[5], acc[6], acc[7]};
            d4[2] = (float4){acc[8], acc[9], acc[10], acc[11]};
            d4[3] = (float4){acc[12], acc[13], acc[14], acc[15]};
        }
        __syncthreads();
        if (half == 0) {
            accum_q16(acc, qself, wself);
            const float* pb = &pB[nslot][ln * 16];
            union { ushort us[16]; uint4 u[2]; } pk;
#pragma unroll
            for (int i = 0; i < 16; ++i) pk.us[i] = f2bf_bits(acc[i] + pb[i]);
            sA[nslot * 17 + 2 * ln] = pk.u[0];
            sA[nslot * 17 + 2 * ln + 1] = pk.u[1];
        }
    }
    __syncthreads();

    // ---- phase 2: MFMA 16x128 tile; wave wv owns col-tiles 2wv, 2wv+1 ----
    int q = lane >> 4, m = lane & 15;
    f32x4 c0 = (f32x4){0.f, 0.f, 0.f, 0.f};
    f32x4 c1 = (f32x4){0.f, 0.f, 0.f, 0.f};
    int n0 = 16 * (2 * wv), n1 = 16 * (2 * wv + 1);
#pragma unroll
    for (int kk = 0; kk < 4; ++kk) {
        bf16x8 af = *(const bf16x8*)&sA[m * 17 + kk * 4 + q];
        bf16x8 b0 = *(const bf16x8*)(Wt + (n0 + m) * DD + kk * 32 + q * 8);
        bf16x8 b1 = *(const bf16x8*)(Wt + (n1 + m) * DD + kk * 32 + q * 8);
        c0 = __builtin_amdgcn_mfma_f32_16x16x32_bf16(af, b0, c0, 0, 0, 0);
        c1 = __builtin_amdgcn_mfma_f32_16x16x32_bf16(af, b1, c1, 0, 0, 0);
    }

    // ---- epilogue: bias + LN + ReLU + residual; non-final layers also emit int8 ----
    float bb0 = bias[n0 + m], bb1 = bias[n1 + m];
    float s1[4], s2[4];
#pragma unroll
    for (int r = 0; r < 4; ++r) {
        float v0 = c0[r] + bb0, v1 = c1[r] + bb1;
        c0[r] = v0; c1[r] = v1;
        s1[r] = v0 + v1;
        s2[r] = v0 * v0 + v1 * v1;
    }
#pragma unroll
    for (int off = 1; off <= 8; off <<= 1) {
#pragma unroll
        for (int r = 0; r < 4; ++r) {
            s1[r] += __shfl_xor(s1[r], off, 64);
            s2[r] += __shfl_xor(s2[r], off, 64);
        }
    }
    if (m == 0) {
#pragma unroll
        for (int r = 0; r < 4; ++r) {
            sLN1[wv][q * 4 + r] = s1[r];
            sLN2[wv][q * 4 + r] = s2[r];
        }
    }
    __syncthreads();
    float ga0 = gamma[n0 + m], ga1 = gamma[n1 + m];
    float be0 = beta[n0 + m], be1 = beta[n1 + m];
    float o0v[4], o1v[4], rmax[4];
#pragma unroll
    for (int r = 0; r < 4; ++r) {
        int row = q * 4 + r;
        float S1 = sLN1[0][row] + sLN1[1][row] + sLN1[2][row] + sLN1[3][row];
        float S2 = sLN2[0][row] + sLN2[1][row] + sLN2[2][row] + sLN2[3][row];
        float mu = S1 * (1.f / 128.f);
        float var = S2 * (1.f / 128.f) - mu * mu;
        float rstd = rsqrtf(var + LN_EPS);
        int nd = sNode[row];
        size_t rb = (size_t)nd * DD;
        float o0 = fmaxf((c0[r] - mu) * rstd * ga0 + be0, 0.f);
        float o1 = fmaxf((c1[r] - mu) * rstd * ga1 + be1, 0.f);
        if (RES) {
            o0 += __uint_as_float(((uint)fin[rb + n0 + m]) << 16);
            o1 += __uint_as_float(((uint)fin[rb + n1 + m]) << 16);
        }
        if (FINAL) {
            out[rb + n0 + m] = o0;
            out[rb + n1 + m] = o1;
        } else {
            fout[rb + n0 + m] = f2bf_bits(o0);
            fout[rb + n1 + m] = f2bf_bits(o1);
            o0v[r] = o0; o1v[r] = o1;
            rmax[r] = fmaxf(o0, o1);  // o >= 0
        }
    }
    if (!FINAL) {
#pragma unroll
        for (int off = 1; off <= 8; off <<= 1) {
#pragma unroll
            for (int r = 0; r < 4; ++r) rmax[r] = fmaxf(rmax[r], __shfl_xor(rmax[r], off, 64));
        }
        if (m == 0) {
#pragma unroll
            for (int r = 0; r < 4; ++r) sMX[wv][q * 4 + r] = rmax[r];
        }
        __syncthreads();
#pragma unroll
        for (int r = 0; r < 4; ++r) {
            int row = q * 4 + r;
            float M = fmaxf(fmaxf(sMX[0][row], sMX[1][row]), fmaxf(sMX[2][row], sMX[3][row]));
            float inv = 127.f / fmaxf(M, 1e-20f);
            int nd = sNode[row];
            if (wv == 0 && m == 0) scout[nd] = M / 127.f;
            size_t rb = (size_t)nd * DD;
            int q0 = min(__float2int_rn(o0v[r] * inv), 127);
            int q1 = min(__float2int_rn(o1v[r] * inv), 127);
            qfout[rb + n0 + m] = (char)q0;
            qfout[rb + n1 + m] = (char)q1;
        }
    }
}

// ---------------- launch ----------------

extern "C" void kernel_launch(void* const* d_in, const int* in_sizes, int n_in,
                              void* d_out, int out_size, void* d_ws, size_t ws_size,
                              hipStream_t stream) {
    const float* x = (const float*)d_in[0];
    const int* edge = (const int*)d_in[1];
    const float* Ws = (const float*)d_in[2];
    const float* bs = (const float*)d_in[3];
    const float* gs = (const float*)d_in[4];
    const float* bes = (const float*)d_in[5];
    float* out = (float*)d_out;
    const int* src = edge;
    const int* dst = edge + NE;

    char* p = (char*)d_ws;
    int* counts = (int*)p;      p += (size_t)NN * 4;      // scanned in place -> excl
    int* bsums = (int*)p;       p += 1024 * 4;
    int* row_ptr = (int*)p;     p += (size_t)(NN + 4) * 4;
    int* rank = (int*)p;        p += (size_t)NE * 4;      // within-node rank per edge
    float* dinv = (float*)p;    p += (size_t)NN * 4;
    int* degarr = (int*)p;      p += (size_t)NN * 4;
    int* bh = (int*)p;          p += (size_t)PH * 4;
    int* perm = (int*)p;        p += (size_t)NN * 4;
    int2* edge2 = (int2*)p;     p += (size_t)(NE + 8) * 8;  // +8 slack entries
    ushort* fb0 = (ushort*)p;   p += (size_t)NN * DD * 2;   // bf16 residual chain
    ushort* fb1 = (ushort*)p;   p += (size_t)NN * DD * 2;
    char* qf0 = (char*)p;       p += (size_t)NN * DD;       // int8 gather tables
    char* qf1 = (char*)p;       p += (size_t)NN * DD;
    float* sc0 = (float*)p;     p += (size_t)NN * 4;        // per-row scales
    float* sc1 = (float*)p;     p += (size_t)NN * 4;
    ushort* Wt = (ushort*)p;    p += (size_t)3 * DD * DD * 2;

    hipMemsetAsync(counts, 0, (size_t)NN * 4, stream);
    hist_cast_kernel<<<HHB + QB + WB, 256, 0, stream>>>(dst, counts, rank, x,
                                                        (uint2*)qf0, sc0, Ws, Wt);
    scan1024_blocks<<<NSB, 1024, 0, stream>>>(counts, bsums);
    scan_sums1024<<<1, 1024, 0, stream>>>(bsums, NSB);
    finalize_kernel<<<NB, 256, 0, stream>>>(counts, bsums, row_ptr, dinv, degarr, bh);
    permscan_kernel<<<1, 1024, 0, stream>>>(bh);
    scatter_fill_kernel<<<NB + NSL, 256, 0, stream>>>(degarr, bh, perm, src, dst, counts,
                                                      bsums, rank, dinv, edge2);

    layer_kernel<false, false><<<LG, 256, 0, stream>>>(
        (const uint4*)qf0, sc0, fb0, row_ptr, edge2, perm, dinv, Wt, bs, gs, bes,
        fb1, qf1, sc1, out);
    layer_kernel<true, false><<<LG, 256, 0, stream>>>(
        (const uint4*)qf1, sc1, fb1, row_ptr, edge2, perm, dinv, Wt + 16384, bs + DD, gs + DD,
        bes + DD, fb0, qf0, sc0, out);
    layer_kernel<true, true><<<LG, 256, 0, stream>>>(
        (const uint4*)qf0, sc0, fb0, row_ptr, edge2, perm, dinv, Wt + 32768, bs + 2 * DD,
        gs + 2 * DD, bes + 2 * DD, fb1, qf1, sc1, out);
}

// Round 13
// 276.220 us; speedup vs baseline: 1.2436x; 1.2436x over previous
//
#include <hip/hip_runtime.h>
#include <hip/hip_bf16.h>

#define NN 50000
#define NE 800000
#define DD 128
#define NB 196             // ceil(NN/256)
#define NSB 49             // ceil(NN/1024)
#define PH (64 * NB)       // degree-bucket histogram size = 12544
#define FS 1024            // edges per slice (hist + fill partitioning)
#define NSL 782            // ceil(NE/FS)
#define HHB NSL            // hist blocks (each edge read ONCE)
#define QB 3125            // quant-cast blocks (NN/16)
#define WB 192             // wtcast blocks
#define LG 3125            // layer grid (16 nodes/block, 256 threads)
#define LN_EPS 1e-5f

typedef __bf16 bf16x8 __attribute__((ext_vector_type(8)));
typedef float f32x4 __attribute__((ext_vector_type(4)));

__device__ inline ushort f2bf_bits(float f) {
    union { __hip_bfloat16 h; ushort u; } c;
    c.h = __float2bfloat16(f);
    return c.u;
}

// dequant-accumulate 16 int8 lanes of one uint4 with weight ww
__device__ inline void accum_q16(float* acc, uint4 v, float ww) {
    uint q0 = v.x, q1 = v.y, q2 = v.z, q3 = v.w;
    acc[0]  = fmaf(ww, (float)(char)(q0), acc[0]);
    acc[1]  = fmaf(ww, (float)(char)(q0 >> 8), acc[1]);
    acc[2]  = fmaf(ww, (float)(char)(q0 >> 16), acc[2]);
    acc[3]  = fmaf(ww, (float)(char)(q0 >> 24), acc[3]);
    acc[4]  = fmaf(ww, (float)(char)(q1), acc[4]);
    acc[5]  = fmaf(ww, (float)(char)(q1 >> 8), acc[5]);
    acc[6]  = fmaf(ww, (float)(char)(q1 >> 16), acc[6]);
    acc[7]  = fmaf(ww, (float)(char)(q1 >> 24), acc[7]);
    acc[8]  = fmaf(ww, (float)(char)(q2), acc[8]);
    acc[9]  = fmaf(ww, (float)(char)(q2 >> 8), acc[9]);
    acc[10] = fmaf(ww, (float)(char)(q2 >> 16), acc[10]);
    acc[11] = fmaf(ww, (float)(char)(q2 >> 24), acc[11]);
    acc[12] = fmaf(ww, (float)(char)(q3), acc[12]);
    acc[13] = fmaf(ww, (float)(char)(q3 >> 8), acc[13]);
    acc[14] = fmaf(ww, (float)(char)(q3 >> 16), acc[14]);
    acc[15] = fmaf(ww, (float)(char)(q3 >> 24), acc[15]);
}

// ---- fused: single-pass hist (rank-capturing, each edge read ONCE) + int8 row-quant
// cast + Wt cast ---- (r8 structure verbatim: best measured preamble)
__global__ void hist_cast_kernel(const int* __restrict__ dst, int* __restrict__ counts,
                                 int* __restrict__ rank, const float* __restrict__ x,
                                 uint2* __restrict__ qf0, float* __restrict__ sc0,
                                 const float* __restrict__ W, ushort* __restrict__ Wt) {
    int b = blockIdx.x;
    if (b < HHB) {
        int base = b * FS;
#pragma unroll 4
        for (int i = threadIdx.x; i < FS; i += 256) {
            int e = base + i;
            if (e < NE) rank[e] = atomicAdd(&counts[dst[e]], 1);
        }
    } else if (b < HHB + QB) {
        // per-node int8 quantization: 16 lanes x 8 floats = one 128-elem row
        int bb = b - HHB;
        int group = threadIdx.x >> 4, t = threadIdx.x & 15;
        int node = bb * 16 + group;  // 3125*16 = 50000 exact
        const float4* xr = (const float4*)(x + (size_t)node * DD + t * 8);
        float4 v0 = xr[0], v1 = xr[1];
        float vals[8] = {v0.x, v0.y, v0.z, v0.w, v1.x, v1.y, v1.z, v1.w};
        float am = 0.f;
#pragma unroll
        for (int i = 0; i < 8; ++i) am = fmaxf(am, fabsf(vals[i]));
#pragma unroll
        for (int off = 1; off <= 8; off <<= 1) am = fmaxf(am, __shfl_xor(am, off, 64));
        float inv = 127.f / fmaxf(am, 1e-20f);
        uint lo = 0, hi = 0;
#pragma unroll
        for (int i = 0; i < 4; ++i) {
            int q = __float2int_rn(vals[i] * inv);
            lo |= ((uint)(q & 0xff)) << (8 * i);
        }
#pragma unroll
        for (int i = 0; i < 4; ++i) {
            int q = __float2int_rn(vals[4 + i] * inv);
            hi |= ((uint)(q & 0xff)) << (8 * i);
        }
        uint2 pk; pk.x = lo; pk.y = hi;
        qf0[node * 16 + t] = pk;
        if (t == 0) sc0[node] = am / 127.f;
    } else {
        int i = (b - HHB - QB) * 256 + threadIdx.x;  // 3*128*128 = 49152
        int l = i >> 14, k = (i >> 7) & 127, n = i & 127;
        Wt[l * 16384 + n * 128 + k] = f2bf_bits(W[i]);
    }
}

// level-0 scan over NN elements, 1024 threads/block, in-place; emits block sums
__global__ __launch_bounds__(1024) void scan1024_blocks(int* __restrict__ data,
                                                        int* __restrict__ bsums) {
    __shared__ int ws[16];
    int gid = blockIdx.x * 1024 + threadIdx.x;
    int lane = threadIdx.x & 63, wid = threadIdx.x >> 6;
    int v = (gid < NN) ? data[gid] : 0;
    int x = v;
#pragma unroll
    for (int off = 1; off < 64; off <<= 1) {
        int t = __shfl_up(x, off, 64);
        if (lane >= off) x += t;
    }
    if (lane == 63) ws[wid] = x;
    __syncthreads();
    if (threadIdx.x == 0) {
        int run = 0;
        for (int i = 0; i < 16; ++i) { int t = ws[i]; ws[i] = run; run += t; }
        bsums[blockIdx.x] = run;
    }
    __syncthreads();
    if (gid < NN) data[gid] = x - v + ws[wid];
}

// level-1: single block scans the 49 block sums
__global__ __launch_bounds__(1024) void scan_sums1024(int* __restrict__ bsums, int nb) {
    __shared__ int ws[16];
    int tid = threadIdx.x;
    int lane = tid & 63, wid = tid >> 6;
    int v = (tid < nb) ? bsums[tid] : 0;
    int x = v;
#pragma unroll
    for (int off = 1; off < 64; off <<= 1) {
        int t = __shfl_up(x, off, 64);
        if (lane >= off) x += t;
    }
    if (lane == 63) ws[wid] = x;
    __syncthreads();
    if (tid == 0) {
        int run = 0;
        for (int i = 0; i < 16; ++i) { int t = ws[i]; ws[i] = run; run += t; }
    }
    __syncthreads();
    if (tid < nb) bsums[tid] = x - v + ws[wid];
}

// row_ptr, degree, dinv + degree histogram (bins reversed -> longest-job-first layer
// scheduling; numerics unaffected).
__global__ void finalize_kernel(const int* __restrict__ excl, const int* __restrict__ bsums,
                                int* __restrict__ row_ptr, float* __restrict__ dinv,
                                int* __restrict__ degarr, int* __restrict__ bh) {
    __shared__ int lh[64];
    if (threadIdx.x < 64) lh[threadIdx.x] = 0;
    __syncthreads();
    int d = blockIdx.x * 256 + threadIdx.x;
    if (d < NN) {
        int p0 = excl[d] + bsums[d >> 10];
        int nxt = (d == NN - 1) ? NE : excl[d + 1] + bsums[(d + 1) >> 10];
        int deg = nxt - p0;
        row_ptr[d] = p0;
        dinv[d] = rsqrtf((float)deg + 1.0f);
        degarr[d] = deg;
        atomicAdd(&lh[63 - min(deg, 63)], 1);
    }
    __syncthreads();
    if (threadIdx.x < 64) bh[threadIdx.x * NB + blockIdx.x] = lh[threadIdx.x];
    if (blockIdx.x == 0 && threadIdx.x == 0) row_ptr[NN] = NE;
}

__global__ __launch_bounds__(1024) void permscan_kernel(int* __restrict__ bh) {
    __shared__ int wsum[16];
    const int CH = 13;  // 1024*13 = 13312 >= 12544
    int tid = threadIdx.x;
    int base = tid * CH;
    int vals[CH];
    int s = 0;
#pragma unroll
    for (int i = 0; i < CH; ++i) {
        int idx = base + i;
        int v = (idx < PH) ? bh[idx] : 0;
        vals[i] = s;
        s += v;
    }
    int lane = tid & 63, wid = tid >> 6;
    int x = s;
#pragma unroll
    for (int off = 1; off < 64; off <<= 1) {
        int t = __shfl_up(x, off, 64);
        if (lane >= off) x += t;
    }
    if (lane == 63) wsum[wid] = x;
    __syncthreads();
    if (tid == 0) {
        int run = 0;
        for (int i = 0; i < 16; ++i) { int t = wsum[i]; wsum[i] = run; run += t; }
    }
    __syncthreads();
    int texcl = x - s + wsum[wid];
#pragma unroll
    for (int i = 0; i < CH; ++i) {
        int idx = base + i;
        if (idx < PH) bh[idx] = texcl + vals[i];
    }
}

// merged: blocks [0,NB) = degree-bucket permscatter (descending degree); blocks [NB,..) =
// single-pass fill (each edge read ONCE), atomic-free: pos = excl[d] + bsums + rank[e].
// Block NB zero-inits 8 edge2 slack entries (safe over-read for the last node's batches).
__global__ void scatter_fill_kernel(const int* __restrict__ degarr, const int* __restrict__ bh,
                                    int* __restrict__ perm, const int* __restrict__ src,
                                    const int* __restrict__ dst, const int* __restrict__ excl,
                                    const int* __restrict__ bsums, const int* __restrict__ rank,
                                    const float* __restrict__ dinv, int2* __restrict__ edge2) {
    if (blockIdx.x < NB) {
        __shared__ int lh[64];
        __shared__ int lbase[64];
        if (threadIdx.x < 64) {
            lh[threadIdx.x] = 0;
            lbase[threadIdx.x] = bh[threadIdx.x * NB + blockIdx.x];
        }
        __syncthreads();
        int gid = blockIdx.x * 256 + threadIdx.x;
        if (gid < NN) {
            int b = 63 - min(degarr[gid], 63);
            int r = atomicAdd(&lh[b], 1);
            perm[lbase[b] + r] = gid;
        }
    } else {
        int bb = blockIdx.x - NB;
        if (bb == 0 && threadIdx.x < 8) {
            int2 z; z.x = 0; z.y = 0;
            edge2[NE + threadIdx.x] = z;
        }
        int base = bb * FS;
#pragma unroll 4
        for (int i = threadIdx.x; i < FS; i += 256) {
            int e = base + i;
            if (e < NE) {
                int d = dst[e];
                int s = src[e];
                int pos = excl[d] + bsums[d >> 10] + rank[e];
                int2 o;
                o.x = s;
                o.y = __float_as_int(dinv[s] * dinv[d]);
                edge2[pos] = o;
            }
        }
    }
}

// ---------------- fused per-layer: int8 gather-aggregate + MFMA GEMM + bias+LN+ReLU+res ----
// SPILL-FREE occupancy retry: each node's edge list is split across TWO ADJACENT 8-lane
// groups OF THE SAME WAVE (lane bit 3 = half). Partial combine = 16x shfl_xor(8) -- no
// LDS, no barrier, no divergent lifetimes. qself loaded unconditionally by both halves
// (same address), weight-masked on half 1. Block = 256 threads = 4 waves = 16 nodes;
// natural VGPR (~52-64) -> up to 32 waves/CU resident (vs 24 with 128-thread blocks).
template <bool RES, bool FINAL>
__global__ __launch_bounds__(256) void layer_kernel(
    const uint4* __restrict__ qin, const float* __restrict__ scin,
    const ushort* __restrict__ fin, const int* __restrict__ row_ptr,
    const int2* __restrict__ edge2, const int* __restrict__ perm,
    const float* __restrict__ dinv, const ushort* __restrict__ Wt,
    const float* __restrict__ bias, const float* __restrict__ gamma,
    const float* __restrict__ beta, ushort* __restrict__ fout, char* __restrict__ qfout,
    float* __restrict__ scout, float* __restrict__ out) {
    __shared__ uint4 sA[16 * 17];
    __shared__ int sNode[16];
    __shared__ float sLN1[4][16], sLN2[4][16];
    __shared__ float sMX[4][16];

    int tid = threadIdx.x;
    int wv = tid >> 6, lane = tid & 63;
    int grp8 = lane >> 3, ln = lane & 7;
    int gg = wv * 8 + grp8;          // 0..31 (8-lane group id)
    int nslot = gg >> 1, half = gg & 1;
    int slot = blockIdx.x * 16 + nslot;  // grid 3125*16 = 50000 exact
    int node = perm[slot];
    if (ln == 0 && half == 0) sNode[nslot] = node;

    // ---- phase 1: int8 gather-aggregate, 2 same-wave groups per node ----
    {
        int beg = row_ptr[node], deg = row_ptr[node + 1] - beg;
        int nbt = (deg + 7) >> 3;
        int nb2 = (nbt + 1) >> 1;
        int bA = half * nb2;
        int bZ = half ? nbt : nb2;
        float acc[16] = {};

        uint4 qself = qin[node * 8 + ln];  // both halves: same address, L1-coalesced
        float di = dinv[node];
        float wself = half ? 0.f : di * di * scin[node];  // masked on half 1

        const int2* eb = edge2 + beg;
        int bsel = lane & 56;
        for (int b = bA; b < bZ; ++b) {
            int lim = deg - b * 8;  // >= 1 for all executed batches
            int2 a = eb[b * 8 + ln];  // own edge (over-read covered by edge2 slack)
            float wf = __int_as_float(a.y) * scin[a.x];
            int sj[8];
            float W8[8];
#pragma unroll
            for (int j = 0; j < 8; ++j) sj[j] = __shfl(a.x, bsel + j, 64);
#pragma unroll
            for (int j = 0; j < 8; ++j) W8[j] = __shfl(wf, bsel + j, 64);
            uint4 Q[8];
#pragma unroll
            for (int j = 0; j < 8; ++j) Q[j] = qin[sj[j] * 8 + ln];
#pragma unroll
            for (int j = 0; j < 8; ++j) accum_q16(acc, Q[j], (j < lim) ? W8[j] : 0.f);
        }
        accum_q16(acc, qself, wself);

        // combine the two halves: partner lane is lane^8 (adjacent 8-lane group)
#pragma unroll
        for (int i = 0; i < 16; ++i) acc[i] += __shfl_xor(acc[i], 8, 64);

        if (half == 0) {
            union { ushort us[16]; uint4 u[2]; } pk;
#pragma unroll
            for (int i = 0; i < 16; ++i) pk.us[i] = f2bf_bits(acc[i]);
            sA[nslot * 17 + 2 * ln] = pk.u[0];
            sA[nslot * 17 + 2 * ln + 1] = pk.u[1];
        }
    }
    __syncthreads();

    // ---- phase 2: MFMA 16x128 tile; wave wv owns col-tiles 2wv, 2wv+1 ----
    int q = lane >> 4, m = lane & 15;
    f32x4 c0 = (f32x4){0.f, 0.f, 0.f, 0.f};
    f32x4 c1 = (f32x4){0.f, 0.f, 0.f, 0.f};
    int n0 = 16 * (2 * wv), n1 = 16 * (2 * wv + 1);
#pragma unroll
    for (int kk = 0; kk < 4; ++kk) {
        bf16x8 af = *(const bf16x8*)&sA[m * 17 + kk * 4 + q];
        bf16x8 b0 = *(const bf16x8*)(Wt + (n0 + m) * DD + kk * 32 + q * 8);
        bf16x8 b1 = *(const bf16x8*)(Wt + (n1 + m) * DD + kk * 32 + q * 8);
        c0 = __builtin_amdgcn_mfma_f32_16x16x32_bf16(af, b0, c0, 0, 0, 0);
        c1 = __builtin_amdgcn_mfma_f32_16x16x32_bf16(af, b1, c1, 0, 0, 0);
    }

    // ---- epilogue: bias + LN + ReLU + residual; non-final layers also emit int8 ----
    float bb0 = bias[n0 + m], bb1 = bias[n1 + m];
    float s1[4], s2[4];
#pragma unroll
    for (int r = 0; r < 4; ++r) {
        float v0 = c0[r] + bb0, v1 = c1[r] + bb1;
        c0[r] = v0; c1[r] = v1;
        s1[r] = v0 + v1;
        s2[r] = v0 * v0 + v1 * v1;
    }
#pragma unroll
    for (int off = 1; off <= 8; off <<= 1) {
#pragma unroll
        for (int r = 0; r < 4; ++r) {
            s1[r] += __shfl_xor(s1[r], off, 64);
            s2[r] += __shfl_xor(s2[r], off, 64);
        }
    }
    if (m == 0) {
#pragma unroll
        for (int r = 0; r < 4; ++r) {
            sLN1[wv][q * 4 + r] = s1[r];
            sLN2[wv][q * 4 + r] = s2[r];
        }
    }
    __syncthreads();
    float ga0 = gamma[n0 + m], ga1 = gamma[n1 + m];
    float be0 = beta[n0 + m], be1 = beta[n1 + m];
    float o0v[4], o1v[4], rmax[4];
#pragma unroll
    for (int r = 0; r < 4; ++r) {
        int row = q * 4 + r;
        float S1 = sLN1[0][row] + sLN1[1][row] + sLN1[2][row] + sLN1[3][row];
        float S2 = sLN2[0][row] + sLN2[1][row] + sLN2[2][row] + sLN2[3][row];
        float mu = S1 * (1.f / 128.f);
        float var = S2 * (1.f / 128.f) - mu * mu;
        float rstd = rsqrtf(var + LN_EPS);
        int nd = sNode[row];
        size_t rb = (size_t)nd * DD;
        float o0 = fmaxf((c0[r] - mu) * rstd * ga0 + be0, 0.f);
        float o1 = fmaxf((c1[r] - mu) * rstd * ga1 + be1, 0.f);
        if (RES) {
            o0 += __uint_as_float(((uint)fin[rb + n0 + m]) << 16);
            o1 += __uint_as_float(((uint)fin[rb + n1 + m]) << 16);
        }
        if (FINAL) {
            out[rb + n0 + m] = o0;
            out[rb + n1 + m] = o1;
        } else {
            fout[rb + n0 + m] = f2bf_bits(o0);
            fout[rb + n1 + m] = f2bf_bits(o1);
            o0v[r] = o0; o1v[r] = o1;
            rmax[r] = fmaxf(o0, o1);  // o >= 0
        }
    }
    if (!FINAL) {
#pragma unroll
        for (int off = 1; off <= 8; off <<= 1) {
#pragma unroll
            for (int r = 0; r < 4; ++r) rmax[r] = fmaxf(rmax[r], __shfl_xor(rmax[r], off, 64));
        }
        if (m == 0) {
#pragma unroll
            for (int r = 0; r < 4; ++r) sMX[wv][q * 4 + r] = rmax[r];
        }
        __syncthreads();
#pragma unroll
        for (int r = 0; r < 4; ++r) {
            int row = q * 4 + r;
            float M = fmaxf(fmaxf(sMX[0][row], sMX[1][row]), fmaxf(sMX[2][row], sMX[3][row]));
            float inv = 127.f / fmaxf(M, 1e-20f);
            int nd = sNode[row];
            if (wv == 0 && m == 0) scout[nd] = M / 127.f;
            size_t rb = (size_t)nd * DD;
            int q0 = min(__float2int_rn(o0v[r] * inv), 127);
            int q1 = min(__float2int_rn(o1v[r] * inv), 127);
            qfout[rb + n0 + m] = (char)q0;
            qfout[rb + n1 + m] = (char)q1;
        }
    }
}

// ---------------- launch ----------------

extern "C" void kernel_launch(void* const* d_in, const int* in_sizes, int n_in,
                              void* d_out, int out_size, void* d_ws, size_t ws_size,
                              hipStream_t stream) {
    const float* x = (const float*)d_in[0];
    const int* edge = (const int*)d_in[1];
    const float* Ws = (const float*)d_in[2];
    const float* bs = (const float*)d_in[3];
    const float* gs = (const float*)d_in[4];
    const float* bes = (const float*)d_in[5];
    float* out = (float*)d_out;
    const int* src = edge;
    const int* dst = edge + NE;

    char* p = (char*)d_ws;
    int* counts = (int*)p;      p += (size_t)NN * 4;      // scanned in place -> excl
    int* bsums = (int*)p;       p += 1024 * 4;
    int* row_ptr = (int*)p;     p += (size_t)(NN + 4) * 4;
    int* rank = (int*)p;        p += (size_t)NE * 4;      // within-node rank per edge
    float* dinv = (float*)p;    p += (size_t)NN * 4;
    int* degarr = (int*)p;      p += (size_t)NN * 4;
    int* bh = (int*)p;          p += (size_t)PH * 4;
    int* perm = (int*)p;        p += (size_t)NN * 4;
    int2* edge2 = (int2*)p;     p += (size_t)(NE + 8) * 8;  // +8 slack entries
    ushort* fb0 = (ushort*)p;   p += (size_t)NN * DD * 2;   // bf16 residual chain
    ushort* fb1 = (ushort*)p;   p += (size_t)NN * DD * 2;
    char* qf0 = (char*)p;       p += (size_t)NN * DD;       // int8 gather tables
    char* qf1 = (char*)p;       p += (size_t)NN * DD;
    float* sc0 = (float*)p;     p += (size_t)NN * 4;        // per-row scales
    float* sc1 = (float*)p;     p += (size_t)NN * 4;
    ushort* Wt = (ushort*)p;    p += (size_t)3 * DD * DD * 2;

    hipMemsetAsync(counts, 0, (size_t)NN * 4, stream);
    hist_cast_kernel<<<HHB + QB + WB, 256, 0, stream>>>(dst, counts, rank, x,
                                                        (uint2*)qf0, sc0, Ws, Wt);
    scan1024_blocks<<<NSB, 1024, 0, stream>>>(counts, bsums);
    scan_sums1024<<<1, 1024, 0, stream>>>(bsums, NSB);
    finalize_kernel<<<NB, 256, 0, stream>>>(counts, bsums, row_ptr, dinv, degarr, bh);
    permscan_kernel<<<1, 1024, 0, stream>>>(bh);
    scatter_fill_kernel<<<NB + NSL, 256, 0, stream>>>(degarr, bh, perm, src, dst, counts,
                                                      bsums, rank, dinv, edge2);

    layer_kernel<false, false><<<LG, 256, 0, stream>>>(
        (const uint4*)qf0, sc0, fb0, row_ptr, edge2, perm, dinv, Wt, bs, gs, bes,
        fb1, qf1, sc1, out);
    layer_kernel<true, false><<<LG, 256, 0, stream>>>(
        (const uint4*)qf1, sc1, fb1, row_ptr, edge2, perm, dinv, Wt + 16384, bs + DD, gs + DD,
        bes + DD, fb0, qf0, sc0, out);
    layer_kernel<true, true><<<LG, 256, 0, stream>>>(
        (const uint4*)qf0, sc0, fb0, row_ptr, edge2, perm, dinv, Wt + 32768, bs + 2 * DD,
        gs + 2 * DD, bes + 2 * DD, fb1, qf1, sc1, out);
}